// Round 7
// baseline (21.467 us; speedup 1.0000x reference)
//
#include <hip/hip_runtime.h>

#define NF 17
#define NN 23
#define ED 16
#define BLK 1024
#define RPP 256      // rows per pass = BLK/4
#define RPB 512      // rows per block (2 passes)
#define SROWS 862    // packed rows of the 14 small-vocab fields
#define SSTR 20      // padded floats per LDS row (80 B)

typedef int   int4u   __attribute__((ext_vector_type(4), aligned(4)));
typedef float float4u __attribute__((ext_vector_type(4), aligned(4)));
typedef float float2u __attribute__((ext_vector_type(2), aligned(4)));

__device__ __forceinline__ void acc4(const float4 v, float& s0, float& s1,
                                     float& s2, float& s3, float& sq) {
    s0 += v.x; s1 += v.y; s2 += v.z; s3 += v.w;
    sq += v.x * v.x + v.y * v.y + v.z * v.z + v.w * v.w;
}

__global__ __launch_bounds__(BLK, 4) void ffm_fwd_kernel(
    const int* __restrict__ x_cat,
    const float* __restrict__ x_num,
    const float* __restrict__ table,
    const float* __restrict__ W_num,
    const float* __restrict__ bias,
    float* __restrict__ out,
    int nrows)
{
    __shared__ float tab[SROWS * SSTR];   // 68,960 B
    __shared__ float wsum[24];            // padded; wsum[23] = 0

    const int tid = threadIdx.x;
    const int rl  = tid >> 2;   // local row within pass
    const int g   = tid & 3;    // dim-group: dims [4g, 4g+4)
    const int wb  = 6 * g;

    const int row0 = blockIdx.x * RPB + rl;
    const int row1 = row0 + RPP;
    const int r0c = (row0 < nrows) ? row0 : (nrows - 1);
    const int r1c = (row1 < nrows) ? row1 : (nrows - 1);

    // ---- Prefetch pass-0 inputs BEFORE staging (stage+barrier hides latency) ----
    const int* xc0 = x_cat + (size_t)r0c * NF;
    int4u a0 = *(const int4u*)(xc0);
    int4u a1 = *(const int4u*)(xc0 + 4);
    int4u a2 = *(const int4u*)(xc0 + 8);
    int4u a3 = *(const int4u*)(xc0 + 12);
    int  a16 = xc0[16];
    const float* xp0 = x_num + (size_t)r0c * NN;
    float4u xa0 = *(const float4u*)(xp0 + wb);
    float xb0_0, xb1_0;
    if (g < 3) { const float2u t = *(const float2u*)(xp0 + wb + 4); xb0_0 = t.x; xb1_0 = t.y; }
    else       { xb0_0 = xp0[22]; xb1_0 = 0.f; }

    if (tid < 24) {
        float a = 0.f;
        if (tid < NN) {
            #pragma unroll
            for (int d = 0; d < ED; ++d) a += W_num[d * NN + tid];
        }
        wsum[tid] = a;
    }

    // ---- Stage the 14 small-vocab fields (862 rows) once per block ----
    for (int i = tid; i < SROWS * 4; i += BLK) {
        const int r = i >> 2, q = i & 3;
        const int d = (r < 653) ? 0 : (r < 787) ? 1000000 : (r < 845) ? 1001001 : 1003001;
        *(float4*)&tab[r * SSTR + q * 4] =
            *(const float4*)(table + (size_t)(r + d) * ED + q * 4);
    }
    __syncthreads();

    const float b0 = bias[0];
    const float w0 = wsum[wb],     w1 = wsum[wb + 1], w2 = wsum[wb + 2],
                w3 = wsum[wb + 3], w4 = wsum[wb + 4], w5 = wsum[wb + 5];

    // ---- Pass 0: issue the 3 big-field gathers immediately ----
    const float4 gv00 = *(const float4*)(table + (size_t)(a1.x +     653) * ED + g * 4);
    const float4 gv01 = *(const float4*)(table + (size_t)(a2.z + 1000787) * ED + g * 4);
    const float4 gv02 = *(const float4*)(table + (size_t)(a3.z + 1001846) * ED + g * 4);

    // ---- Issue pass-1 input loads (independent; fills the f4 latency window) ----
    const int* xc1 = x_cat + (size_t)r1c * NF;
    int4u b0v = *(const int4u*)(xc1);
    int4u b1v = *(const int4u*)(xc1 + 4);
    int4u b2v = *(const int4u*)(xc1 + 8);
    int4u b3v = *(const int4u*)(xc1 + 12);
    int  b16v = xc1[16];
    const float* xp1 = x_num + (size_t)r1c * NN;
    float4u xa1 = *(const float4u*)(xp1 + wb);
    float xb0_1, xb1_1;
    if (g < 3) { const float2u t = *(const float2u*)(xp1 + wb + 4); xb0_1 = t.x; xb1_1 = t.y; }
    else       { xb0_1 = xp1[22]; xb1_1 = 0.f; }

    // ---- Pass 0 LDS math ----
    {
        float lin = xa0.x * w0 + xa0.y * w1 + xa0.z * w2 + xa0.w * w3
                  + xb0_0 * w4 + xb1_0 * w5;
        int pr[14];
        pr[0]  = a0.x;        pr[1]  = 500 + a0.y;  pr[2]  = 550 + a0.z;
        pr[3]  = 650 + a0.w;  pr[4]  = 653 + a1.y;  pr[5]  = 663 + a1.z;
        pr[6]  = 683 + a1.w;  pr[7]  = 783 + a2.x;  pr[8]  = 785 + a2.y;
        pr[9]  = 787 + a2.w;  pr[10] = 791 + a3.x;  pr[11] = 795 + a3.y;
        pr[12] = 845 + a3.w;  pr[13] = 855 + a16;

        float s0 = 0.f, s1 = 0.f, s2 = 0.f, s3 = 0.f, sq = 0.f;
        #pragma unroll
        for (int k = 0; k < 14; ++k)
            acc4(*(const float4*)&tab[pr[k] * SSTR + g * 4], s0, s1, s2, s3, sq);

        // consume the gathers (latency partially covered by the LDS math above)
        acc4(gv00, s0, s1, s2, s3, sq);
        acc4(gv01, s0, s1, s2, s3, sq);
        acc4(gv02, s0, s1, s2, s3, sq);

        float ssum = s0 + s1 + s2 + s3;
        float ss2  = s0 * s0 + s1 * s1 + s2 * s2 + s3 * s3;
        #pragma unroll
        for (int m = 1; m <= 2; m <<= 1) {
            ssum += __shfl_xor(ssum, m);
            ss2  += __shfl_xor(ss2, m);
            sq   += __shfl_xor(sq, m);
            lin  += __shfl_xor(lin, m);
        }
        if (g == 0 && row0 < nrows) out[row0] = b0 + ssum + lin + 0.5f * (ss2 - sq);
    }

    // ---- Pass 1: gathers (indices already resident), then math ----
    const float4 gv10 = *(const float4*)(table + (size_t)(b1v.x +     653) * ED + g * 4);
    const float4 gv11 = *(const float4*)(table + (size_t)(b2v.z + 1000787) * ED + g * 4);
    const float4 gv12 = *(const float4*)(table + (size_t)(b3v.z + 1001846) * ED + g * 4);

    {
        float lin = xa1.x * w0 + xa1.y * w1 + xa1.z * w2 + xa1.w * w3
                  + xb0_1 * w4 + xb1_1 * w5;
        int pr[14];
        pr[0]  = b0v.x;        pr[1]  = 500 + b0v.y;  pr[2]  = 550 + b0v.z;
        pr[3]  = 650 + b0v.w;  pr[4]  = 653 + b1v.y;  pr[5]  = 663 + b1v.z;
        pr[6]  = 683 + b1v.w;  pr[7]  = 783 + b2v.x;  pr[8]  = 785 + b2v.y;
        pr[9]  = 787 + b2v.w;  pr[10] = 791 + b3v.x;  pr[11] = 795 + b3v.y;
        pr[12] = 845 + b3v.w;  pr[13] = 855 + b16v;

        float s0 = 0.f, s1 = 0.f, s2 = 0.f, s3 = 0.f, sq = 0.f;
        #pragma unroll
        for (int k = 0; k < 14; ++k)
            acc4(*(const float4*)&tab[pr[k] * SSTR + g * 4], s0, s1, s2, s3, sq);

        acc4(gv10, s0, s1, s2, s3, sq);
        acc4(gv11, s0, s1, s2, s3, sq);
        acc4(gv12, s0, s1, s2, s3, sq);

        float ssum = s0 + s1 + s2 + s3;
        float ss2  = s0 * s0 + s1 * s1 + s2 * s2 + s3 * s3;
        #pragma unroll
        for (int m = 1; m <= 2; m <<= 1) {
            ssum += __shfl_xor(ssum, m);
            ss2  += __shfl_xor(ss2, m);
            sq   += __shfl_xor(sq, m);
            lin  += __shfl_xor(lin, m);
        }
        if (g == 0 && row1 < nrows) out[row1] = b0 + ssum + lin + 0.5f * (ss2 - sq);
    }
}

extern "C" void kernel_launch(void* const* d_in, const int* in_sizes, int n_in,
                              void* d_out, int out_size, void* d_ws, size_t ws_size,
                              hipStream_t stream) {
    const int*   x_cat = (const int*)  d_in[0];
    const float* x_num = (const float*)d_in[1];
    const float* table = (const float*)d_in[2];
    const float* W_num = (const float*)d_in[3];
    const float* bias  = (const float*)d_in[4];
    float* out = (float*)d_out;

    const int nrows = out_size;                 // 262144
    const int grid = (nrows + RPB - 1) / RPB;   // 512
    ffm_fwd_kernel<<<grid, BLK, 0, stream>>>(x_cat, x_num, table, W_num, bias, out, nrows);
}

// Round 8
// 19.005 us; speedup vs baseline: 1.1296x; 1.1296x over previous
//
#include <hip/hip_runtime.h>

#define NF 17
#define NN 23
#define ED 16
#define BLK 1024
#define RPP 256      // rows per pass = BLK/4
#define RPB 512      // rows per block (2 passes); grid*RPB == nrows exactly
#define SROWS 862    // packed rows of the 14 small-vocab fields
#define SSTR 20      // padded floats per LDS row (80 B)

typedef int   int4u   __attribute__((ext_vector_type(4), aligned(4)));
typedef float float4u __attribute__((ext_vector_type(4), aligned(4)));
typedef float float2u __attribute__((ext_vector_type(2), aligned(4)));

__device__ __forceinline__ void acc4(const float4 v, float& s0, float& s1,
                                     float& s2, float& s3, float& sq) {
    s0 += v.x; s1 += v.y; s2 += v.z; s3 += v.w;
    sq += v.x * v.x + v.y * v.y + v.z * v.z + v.w * v.w;
}

__global__ __launch_bounds__(BLK, 8) void ffm_fwd_kernel(
    const int* __restrict__ x_cat,
    const float* __restrict__ x_num,
    const float* __restrict__ table,
    const float* __restrict__ W_num,
    const float* __restrict__ bias,
    float* __restrict__ out,
    int nrows)
{
    __shared__ float tab[SROWS * SSTR];   // 68,960 B -> 2 blocks/CU
    __shared__ float wsum[24];            // padded; wsum[23] = 0

    const int tid = threadIdx.x;
    const int rl  = tid >> 2;   // local row within pass
    const int g   = tid & 3;    // dim-group: dims [4g, 4g+4)
    const int wb  = 6 * g;

    const int row0 = blockIdx.x * RPB + rl;    // always < nrows (512*512 grid*RPB)
    const int row1 = row0 + RPP;

    // ---- Pass-0 prefetch BEFORE staging: x_cat, then its 3 gathers.
    // The staging loop's vmcnt waits drain these under the barrier phase,
    // so pass-0 consumes with zero exposed latency.
    const int* xc0 = x_cat + (size_t)row0 * NF;
    const int4u a0 = *(const int4u*)(xc0);
    const int4u a1 = *(const int4u*)(xc0 + 4);
    const int4u a2 = *(const int4u*)(xc0 + 8);
    const int4u a3 = *(const int4u*)(xc0 + 12);
    const int  a16 = xc0[16];
    const float4 gv00 = *(const float4*)(table + (size_t)(a1.x +     653) * ED + g * 4);
    const float4 gv01 = *(const float4*)(table + (size_t)(a2.z + 1000787) * ED + g * 4);
    const float4 gv02 = *(const float4*)(table + (size_t)(a3.z + 1001846) * ED + g * 4);

    const float* xp0 = x_num + (size_t)row0 * NN;
    const float4u xa0 = *(const float4u*)(xp0 + wb);
    float xb0_0, xb1_0;
    if (g < 3) { const float2u t = *(const float2u*)(xp0 + wb + 4); xb0_0 = t.x; xb1_0 = t.y; }
    else       { xb0_0 = xp0[22]; xb1_0 = 0.f; }

    if (tid < 24) {
        float a = 0.f;
        if (tid < NN) {
            #pragma unroll
            for (int d = 0; d < ED; ++d) a += W_num[d * NN + tid];
        }
        wsum[tid] = a;
    }

    // ---- Stage the 14 small-vocab fields (862 rows, 55 KB) once per block ----
    for (int i = tid; i < SROWS * 4; i += BLK) {
        const int r = i >> 2, q = i & 3;
        const int d = (r < 653) ? 0 : (r < 787) ? 1000000 : (r < 845) ? 1001001 : 1003001;
        *(float4*)&tab[r * SSTR + q * 4] =
            *(const float4*)(table + (size_t)(r + d) * ED + q * 4);
    }
    __syncthreads();

    const float b0 = bias[0];
    const float w0 = wsum[wb],     w1 = wsum[wb + 1], w2 = wsum[wb + 2],
                w3 = wsum[wb + 3], w4 = wsum[wb + 4], w5 = wsum[wb + 5];

    // ---- Prefetch pass-1 indices (consumed after pass-0; kept outstanding
    // across pass-0's vmcnt(N) gather-consume) ----
    const int* xc1 = x_cat + (size_t)row1 * NF;
    const int4u c0 = *(const int4u*)(xc1);
    const int4u c1 = *(const int4u*)(xc1 + 4);
    const int4u c2 = *(const int4u*)(xc1 + 8);
    const int4u c3 = *(const int4u*)(xc1 + 12);
    const int  c16 = xc1[16];

    // ---- Pass 0 math ----
    {
        float lin = xa0.x * w0 + xa0.y * w1 + xa0.z * w2 + xa0.w * w3
                  + xb0_0 * w4 + xb1_0 * w5;
        int pr[14];
        pr[0]  = a0.x;        pr[1]  = 500 + a0.y;  pr[2]  = 550 + a0.z;
        pr[3]  = 650 + a0.w;  pr[4]  = 653 + a1.y;  pr[5]  = 663 + a1.z;
        pr[6]  = 683 + a1.w;  pr[7]  = 783 + a2.x;  pr[8]  = 785 + a2.y;
        pr[9]  = 787 + a2.w;  pr[10] = 791 + a3.x;  pr[11] = 795 + a3.y;
        pr[12] = 845 + a3.w;  pr[13] = 855 + a16;

        float s0 = 0.f, s1 = 0.f, s2 = 0.f, s3 = 0.f, sq = 0.f;
        #pragma unroll
        for (int k = 0; k < 14; ++k)
            acc4(*(const float4*)&tab[pr[k] * SSTR + g * 4], s0, s1, s2, s3, sq);

        acc4(gv00, s0, s1, s2, s3, sq);
        acc4(gv01, s0, s1, s2, s3, sq);
        acc4(gv02, s0, s1, s2, s3, sq);

        // single-value reduce: every term is additive across the 4 lanes
        float contrib = (s0 + s1 + s2 + s3) + lin
                      + 0.5f * ((s0 * s0 + s1 * s1 + s2 * s2 + s3 * s3) - sq);
        contrib += __shfl_xor(contrib, 1);
        contrib += __shfl_xor(contrib, 2);
        if (g == 0) out[row0] = b0 + contrib;
    }

    // ---- Pass-1 gathers (indices already resident) + x_num ----
    const float4 gv10 = *(const float4*)(table + (size_t)(c1.x +     653) * ED + g * 4);
    const float4 gv11 = *(const float4*)(table + (size_t)(c2.z + 1000787) * ED + g * 4);
    const float4 gv12 = *(const float4*)(table + (size_t)(c3.z + 1001846) * ED + g * 4);

    const float* xp1 = x_num + (size_t)row1 * NN;
    const float4u xa1 = *(const float4u*)(xp1 + wb);
    float xb0_1, xb1_1;
    if (g < 3) { const float2u t = *(const float2u*)(xp1 + wb + 4); xb0_1 = t.x; xb1_1 = t.y; }
    else       { xb0_1 = xp1[22]; xb1_1 = 0.f; }

    // ---- Pass 1 math ----
    {
        float lin = xa1.x * w0 + xa1.y * w1 + xa1.z * w2 + xa1.w * w3
                  + xb0_1 * w4 + xb1_1 * w5;
        int pr[14];
        pr[0]  = c0.x;        pr[1]  = 500 + c0.y;  pr[2]  = 550 + c0.z;
        pr[3]  = 650 + c0.w;  pr[4]  = 653 + c1.y;  pr[5]  = 663 + c1.z;
        pr[6]  = 683 + c1.w;  pr[7]  = 783 + c2.x;  pr[8]  = 785 + c2.y;
        pr[9]  = 787 + c2.w;  pr[10] = 791 + c3.x;  pr[11] = 795 + c3.y;
        pr[12] = 845 + c3.w;  pr[13] = 855 + c16;

        float s0 = 0.f, s1 = 0.f, s2 = 0.f, s3 = 0.f, sq = 0.f;
        #pragma unroll
        for (int k = 0; k < 14; ++k)
            acc4(*(const float4*)&tab[pr[k] * SSTR + g * 4], s0, s1, s2, s3, sq);

        acc4(gv10, s0, s1, s2, s3, sq);
        acc4(gv11, s0, s1, s2, s3, sq);
        acc4(gv12, s0, s1, s2, s3, sq);

        float contrib = (s0 + s1 + s2 + s3) + lin
                      + 0.5f * ((s0 * s0 + s1 * s1 + s2 * s2 + s3 * s3) - sq);
        contrib += __shfl_xor(contrib, 1);
        contrib += __shfl_xor(contrib, 2);
        if (g == 0) out[row1] = b0 + contrib;
    }
}

extern "C" void kernel_launch(void* const* d_in, const int* in_sizes, int n_in,
                              void* d_out, int out_size, void* d_ws, size_t ws_size,
                              hipStream_t stream) {
    const int*   x_cat = (const int*)  d_in[0];
    const float* x_num = (const float*)d_in[1];
    const float* table = (const float*)d_in[2];
    const float* W_num = (const float*)d_in[3];
    const float* bias  = (const float*)d_in[4];
    float* out = (float*)d_out;

    const int nrows = out_size;                 // 262144
    const int grid = (nrows + RPB - 1) / RPB;   // 512
    ffm_fwd_kernel<<<grid, BLK, 0, stream>>>(x_cat, x_num, table, W_num, bias, out, nrows);
}